// Round 12
// baseline (99.099 us; speedup 1.0000x reference)
//
#include <hip/hip_runtime.h>
#include <math.h>

// ---------------------------------------------------------------------------
// HessianLoss — march + face-payload sharing (exact R9 structure).
// Single change vs R9: __launch_bounds__(256, 4) -> 128-VGPR cap, bumping
// occupancy 3 -> 4 waves/SIMD (natural allocation was 136; 6% squeeze).
// R10 lesson: the (256,3)=170 cap was inert; its reorder/slimming hurt.
// R11 lesson: MK=8 halves wave count -> latency hiding collapses (occ 8%).
// Face/role table (math identical to verified R6-R11):
//   F1=f1@(r,c) i0      F2=f2@(r,c) i0      F3=f1@(r,c-1) i1
//   F4=f1@(r-1,c-1) i2  F5=f2@(r-1,c-1) i1  F6=f2@(r-1,c) i2
// Lane 0 of each wave is a GHOST column (payload producer only).
// Degenerate/clamped faces give NaN payloads; all such uses are guarded.
// No __threadfence (R3-R5: agent fence = L2 invalidate, +80us). No LDS
// staging (R3: inputs are L2/L3-resident).
// ---------------------------------------------------------------------------

struct FP { float ex, ey, ez, hx, hy, hz, w[9]; };  // e02, e10, aw=area*g

__device__ __forceinline__ float3 d3(float3 t, float3 v)
{
    return make_float3(t.x - v.x, t.y - v.y, t.z - v.z);
}
__device__ __forceinline__ float3 shfl_dn3(float3 v)
{
    return make_float3(__shfl_down(v.x, 1, 64), __shfl_down(v.y, 1, 64),
                       __shfl_down(v.z, 1, 64));
}

__device__ __forceinline__ FP mkface(float3 V0, float3 V1, float3 V2,
                                     float3 D0, float3 D1, float3 D2)
{
    float ax = V2.x - V1.x, ay = V2.y - V1.y, az = V2.z - V1.z;   // v21
    float bx = V0.x - V2.x, by = V0.y - V2.y, bz = V0.z - V2.z;   // v02
    float cx = V1.x - V0.x, cy = V1.y - V0.y, cz = V1.z - V0.z;   // v10
    float nx = ay * bz - az * by;
    float ny = az * bx - ax * bz;
    float nz = ax * by - ay * bx;
    float A2 = nx * nx + ny * ny + nz * nz;
    float invA2 = __builtin_amdgcn_rcpf(A2);
    float sc = 0.5f * __builtin_amdgcn_rsqf(A2);      // area / A2
    float e1x = ny * bz - nz * by, e1y = nz * bx - nx * bz, e1z = nx * by - ny * bx;
    float e2x = ny * cz - nz * cy, e2y = nz * cx - nx * cz, e2z = nx * cy - ny * cx;
    FP f;
    f.ex = e1x * invA2; f.ey = e1y * invA2; f.ez = e1z * invA2;   // e02
    f.hx = e2x * invA2; f.hy = e2y * invA2; f.hz = e2z * invA2;   // e10
    float s1x = e1x * sc, s1y = e1y * sc, s1z = e1z * sc;         // area*e02
    float s2x = e2x * sc, s2y = e2y * sc, s2z = e2z * sc;         // area*e10
    float d1x = D1.x - D0.x, d1y = D1.y - D0.y, d1z = D1.z - D0.z;
    float d2x = D2.x - D0.x, d2y = D2.y - D0.y, d2z = D2.z - D0.z;
    f.w[0] = s1x * d1x + s2x * d2x;
    f.w[1] = s1x * d1y + s2x * d2y;
    f.w[2] = s1x * d1z + s2x * d2z;
    f.w[3] = s1y * d1x + s2y * d2x;
    f.w[4] = s1y * d1y + s2y * d2y;
    f.w[5] = s1y * d1z + s2y * d2z;
    f.w[6] = s1z * d1x + s2z * d2x;
    f.w[7] = s1z * d1y + s2z * d2y;
    f.w[8] = s1z * d1z + s2z * d2z;
    return f;
}

__device__ __forceinline__ FP shfl_up_fp(const FP& f)
{
    FP r;
    r.ex = __shfl_up(f.ex, 1, 64); r.ey = __shfl_up(f.ey, 1, 64);
    r.ez = __shfl_up(f.ez, 1, 64);
    r.hx = __shfl_up(f.hx, 1, 64); r.hy = __shfl_up(f.hy, 1, 64);
    r.hz = __shfl_up(f.hz, 1, 64);
#pragma unroll
    for (int i = 0; i < 9; ++i) r.w[i] = __shfl_up(f.w[i], 1, 64);
    return r;
}

// ROLE: 0 -> i0 (k=-(e02+e10)), 1 -> i1 (k=e02), 2 -> i2 (k=e10)
template <int ROLE>
__device__ __forceinline__ void addc(const FP& f, float acc[6][3])
{
    float K[3];
    if (ROLE == 1)      { K[0] = f.ex; K[1] = f.ey; K[2] = f.ez; }
    else if (ROLE == 2) { K[0] = f.hx; K[1] = f.hy; K[2] = f.hz; }
    else { K[0] = -(f.ex + f.hx); K[1] = -(f.ey + f.hy); K[2] = -(f.ez + f.hz); }
    const int pa[6] = {0, 1, 2, 0, 0, 1};
    const int pb[6] = {0, 1, 2, 1, 2, 2};
#pragma unroll
    for (int p = 0; p < 6; ++p)
#pragma unroll
        for (int cc = 0; cc < 3; ++cc)
            acc[p][cc] += K[pa[p]] * f.w[pb[p] * 3 + cc];
}

__device__ __forceinline__ float sq_acc(const float acc[6][3])
{
    float s1 = 0.0f, s2 = 0.0f;
#pragma unroll
    for (int p = 0; p < 3; ++p)
#pragma unroll
        for (int cc = 0; cc < 3; ++cc) s1 += acc[p][cc] * acc[p][cc];
#pragma unroll
    for (int p = 3; p < 6; ++p)
#pragma unroll
        for (int cc = 0; cc < 3; ++cc) s2 += acc[p][cc] * acc[p][cc];
    return s1 + 2.0f * s2;
}

#define MK 4       // rows marched per thread
#define OUTW 63    // output columns per wave (lane 0 = ghost)
#define BOUT (4 * OUTW)  // 252 output columns per 256-thread block

__global__ __launch_bounds__(256, 4)
void hess_face(const float* __restrict__ vsf, const float* __restrict__ vtf,
               float* __restrict__ partials, int W, int H)
{
    const float3* vs = (const float3*)vsf;
    const float3* vt = (const float3*)vtf;
    const int tid = threadIdx.x, lane = tid & 63, wvid = tid >> 6;
    const int c = blockIdx.x * BOUT + wvid * OUTW + lane - 1;
    const int r0 = blockIdx.y * MK;
    const bool valid = (lane > 0) && (c < W);   // lane>0 => c >= 0
    const bool cp = (c < W - 1), cm = (c > 0);
    const int cL = (c < 0) ? 0 : ((c > W - 1) ? W - 1 : c);
    const int cR = (c + 1 > W - 1) ? W - 1 : ((c + 1 < 0) ? 0 : c + 1);

    // ---- prologue: rows r0-1 (clamped) and r0; build initial F4, F6 ----
    const int otop = (r0 > 0 ? r0 - 1 : 0) * W;
    const int obot = r0 * W;
    float3 V00 = vs[otop + cL];  float3 D00 = d3(vt[otop + cL], V00);
    float3 V10 = vs[obot + cL];  float3 D10 = d3(vt[obot + cL], V10);
    float3 V01 = shfl_dn3(V00),  D01 = shfl_dn3(D00);
    float3 V11 = shfl_dn3(V10),  D11 = shfl_dn3(D10);
    if (lane == 63) {
        float3 v = vs[otop + cR]; V01 = v; D01 = d3(vt[otop + cR], v);
        v = vs[obot + cR];        V11 = v; D11 = d3(vt[obot + cR], v);
    }
    FP F1p = mkface(V00, V01, V11, D00, D01, D11);   // f1@(r0-1,c)
    FP F2p = mkface(V00, V11, V10, D00, D11, D10);   // f2@(r0-1,c)
    FP F4 = shfl_up_fp(F1p);                         // -> f1@(r0-1,c-1)
    FP F6 = F2p;                                     // -> f2@(r0-1,c)
    // advance to rows r0, r0+1
    V00 = V10; D00 = D10; V01 = V11; D01 = D11;
    const int o1 = (r0 + 1 < H ? r0 + 1 : H - 1) * W;
    V10 = vs[o1 + cL]; D10 = d3(vt[o1 + cL], V10);
    V11 = shfl_dn3(V10); D11 = shfl_dn3(D10);
    if (lane == 63) {
        float3 v = vs[o1 + cR]; V11 = v; D11 = d3(vt[o1 + cR], v);
    }

    float s = 0.0f;
#pragma unroll
    for (int k = 0; k < MK; ++k) {
        const int r = r0 + k;
        const bool rp = (r < H - 1), rm = (r > 0);   // wave-uniform

        // prefetch row r+2 (own column; lane-63 also right column)
        const int ob = (r + 2 < H ? r + 2 : H - 1) * W;
        float3 P = vs[ob + cL];
        float3 TP = vt[ob + cL];
        float3 PR = P, TPR = TP;
        if (lane == 63) { PR = vs[ob + cR]; TPR = vt[ob + cR]; }

        // build this row's faces (once per face, owner lane)
        FP F1 = mkface(V00, V01, V11, D00, D01, D11);  // f1@(r,c)
        FP F2 = mkface(V00, V11, V10, D00, D11, D10);  // f2@(r,c)
        FP F3 = shfl_up_fp(F1);                        // f1@(r,c-1)
        FP F5 = shfl_up_fp(F6);                        // f2@(r-1,c-1)

        float acc[6][3] = {};
        if (rp && cp) { addc<0>(F1, acc); addc<0>(F2, acc); }
        if (rp && cm) addc<1>(F3, acc);
        if (rm && cm) { addc<2>(F4, acc); addc<1>(F5, acc); }
        if (rm && cp) addc<2>(F6, acc);
        s += sq_acc(acc);

        // rotate
        V00 = V10; D00 = D10; V01 = V11; D01 = D11;
        V10 = P;   D10 = d3(TP, P);
        V11 = shfl_dn3(V10); D11 = shfl_dn3(D10);
        if (lane == 63) { V11 = PR; D11 = d3(TPR, PR); }
        F4 = F3; F6 = F2;
    }

    if (!valid) s = 0.0f;   // overwrite: kills ghost/out-of-range NaN

    // ---- block reduce + plain partial store ----
#pragma unroll
    for (int o = 32; o > 0; o >>= 1) s += __shfl_down(s, o, 64);
    __shared__ float sm[4];
    if (lane == 0) sm[wvid] = s;
    __syncthreads();
    if (tid == 0)
        partials[blockIdx.y * gridDim.x + blockIdx.x] = sm[0] + sm[1] + sm[2] + sm[3];
}

// ------------- fallback: 1-D per-vertex gather (any grid dims) -------------

__global__ void hess_gather(const float* __restrict__ vsf, const float* __restrict__ vtf,
                            float* __restrict__ partials, int W, int H)
{
    const float3* vs = (const float3*)vsf;
    const float3* vt = (const float3*)vtf;
    int v = blockIdx.x * blockDim.x + threadIdx.x;
    int n = W * H;
    float s = 0.0f;
    if (v < n) {
        int r = v / W;
        int c = v - r * W;
        bool rp = (r < H - 1), rm = (r >= 1), cp = (c < W - 1), cm = (c >= 1);
        int i01 = cp ? v + 1 : v;
        int i11 = (rp && cp) ? v + W + 1 : v;
        int i10 = rp ? v + W : v;
        int im  = cm ? v - 1 : v;
        int idd = (rm && cm) ? v - W - 1 : v;
        int iu  = rm ? v - W : v;
        float3 P00 = vs[v],   D00 = d3(vt[v], P00);
        float3 P01 = vs[i01], D01 = d3(vt[i01], P01);
        float3 P11 = vs[i11], D11 = d3(vt[i11], P11);
        float3 P10 = vs[i10], D10 = d3(vt[i10], P10);
        float3 Pm  = vs[im],  Dm  = d3(vt[im], Pm);
        float3 Pdd = vs[idd], Ddd = d3(vt[idd], Pdd);
        float3 Pu  = vs[iu],  Du  = d3(vt[iu], Pu);
        float acc[6][3] = {};
        if (rp && cp) {
            addc<0>(mkface(P00, P01, P11, D00, D01, D11), acc);
            addc<0>(mkface(P00, P11, P10, D00, D11, D10), acc);
        }
        if (rp && cm)
            addc<1>(mkface(Pm, P00, P10, Dm, D00, D10), acc);
        if (rm && cm) {
            addc<2>(mkface(Pdd, Pu, P00, Ddd, Du, D00), acc);
            addc<1>(mkface(Pdd, P00, Pm, Ddd, D00, Dm), acc);
        }
        if (rm && cp)
            addc<2>(mkface(Pu, P01, P00, Du, D01, D00), acc);
        s = sq_acc(acc);
    }
#pragma unroll
    for (int o = 32; o > 0; o >>= 1) s += __shfl_down(s, o, 64);
    __shared__ float sm[4];
    int lane = threadIdx.x & 63, wid = threadIdx.x >> 6;
    if (lane == 0) sm[wid] = s;
    __syncthreads();
    if (threadIdx.x == 0)
        partials[blockIdx.x] = sm[0] + sm[1] + sm[2] + sm[3];
}

__global__ void finalize_sum(const float* __restrict__ partials, int nparts,
                             float* __restrict__ out, int n)
{
    float s = 0.0f;
    for (int i = threadIdx.x; i < nparts; i += 256) s += partials[i];
#pragma unroll
    for (int o = 32; o > 0; o >>= 1) s += __shfl_down(s, o, 64);
    __shared__ float sm[4];
    int lane = threadIdx.x & 63, wid = threadIdx.x >> 6;
    if (lane == 0) sm[wid] = s;
    __syncthreads();
    if (threadIdx.x == 0)
        out[0] = (sm[0] + sm[1] + sm[2] + sm[3]) / (3.0f * (float)n);
}

// ---------------------------------------------------------------------------

extern "C" void kernel_launch(void* const* d_in, const int* in_sizes, int n_in,
                              void* d_out, int out_size, void* d_ws, size_t ws_size,
                              hipStream_t stream)
{
    const float* vs = (const float*)d_in[0];
    const float* vt = (const float*)d_in[1];
    int n = in_sizes[0] / 3;
    int F = in_sizes[2] / 3;

    int W = (int)(sqrt((double)n) + 0.5);
    int H = (W > 0) ? n / W : 0;
    bool grid_ok = (W > 1) && ((long long)W * H == n) &&
                   (2LL * (W - 1) * (H - 1) == F);

    float* partials = (float*)d_ws;

    if (grid_ok && (H % MK == 0)) {
        dim3 block(256, 1, 1);
        dim3 grid((W + BOUT - 1) / BOUT, H / MK, 1);
        int nparts = grid.x * grid.y;
        hess_face<<<grid, block, 0, stream>>>(vs, vt, partials, W, H);
        finalize_sum<<<1, 256, 0, stream>>>(partials, nparts, (float*)d_out, n);
    } else {
        int threads = 256;
        int blocks = (n + threads - 1) / threads;
        hess_gather<<<blocks, threads, 0, stream>>>(vs, vt, partials, W, H);
        finalize_sum<<<1, 256, 0, stream>>>(partials, blocks, (float*)d_out, n);
    }
}

// Round 13
// 29.044 us; speedup vs baseline: 3.4120x; 3.4120x over previous
//
#include <hip/hip_runtime.h>
#include <math.h>

// ---------------------------------------------------------------------------
// HessianLoss — march + face-payload sharing (exact R9 structure + 2 slims).
// R12 lesson (with R4): ANY __launch_bounds__ min-waves arg collapses this
// kernel to a 64-VGPR granule + catastrophic scratch spill. BANNED.
// This round: R9 byte-identical except two arithmetically-identity slims
// aimed at pushing NATURAL VGPR <= 128 (3 -> 4 waves/SIMD, m69 step):
//   1. F4 carried as h+w only (12) — it is only ever consumed as role i2
//   2. F5 shuffled as e+w only (12) — it is only ever consumed as role i1
// No reorder (R10's reorder discarded), MK=4 (R11: MK=8 halves waves, bad),
// plain __launch_bounds__(256).
// Face/role table (math identical to verified R6-R12):
//   F1=f1@(r,c) i0      F2=f2@(r,c) i0      F3=f1@(r,c-1) i1
//   F4=f1@(r-1,c-1) i2  F5=f2@(r-1,c-1) i1  F6=f2@(r-1,c) i2
// Lane 0 of each wave is a GHOST column (payload producer only).
// Degenerate/clamped faces give NaN payloads; all such uses are guarded.
// No __threadfence (R3-R5: agent fence = L2 invalidate, +80us). No LDS
// staging (R3: inputs are L2/L3-resident).
// ---------------------------------------------------------------------------

struct FP  { float ex, ey, ez, hx, hy, hz, w[9]; };  // e02, e10, aw=area*g
struct FPh { float hx, hy, hz, w[9]; };              // role-i2 carry (F4)

__device__ __forceinline__ float3 d3(float3 t, float3 v)
{
    return make_float3(t.x - v.x, t.y - v.y, t.z - v.z);
}
__device__ __forceinline__ float3 shfl_dn3(float3 v)
{
    return make_float3(__shfl_down(v.x, 1, 64), __shfl_down(v.y, 1, 64),
                       __shfl_down(v.z, 1, 64));
}

__device__ __forceinline__ FP mkface(float3 V0, float3 V1, float3 V2,
                                     float3 D0, float3 D1, float3 D2)
{
    float ax = V2.x - V1.x, ay = V2.y - V1.y, az = V2.z - V1.z;   // v21
    float bx = V0.x - V2.x, by = V0.y - V2.y, bz = V0.z - V2.z;   // v02
    float cx = V1.x - V0.x, cy = V1.y - V0.y, cz = V1.z - V0.z;   // v10
    float nx = ay * bz - az * by;
    float ny = az * bx - ax * bz;
    float nz = ax * by - ay * bx;
    float A2 = nx * nx + ny * ny + nz * nz;
    float invA2 = __builtin_amdgcn_rcpf(A2);
    float sc = 0.5f * __builtin_amdgcn_rsqf(A2);      // area / A2
    float e1x = ny * bz - nz * by, e1y = nz * bx - nx * bz, e1z = nx * by - ny * bx;
    float e2x = ny * cz - nz * cy, e2y = nz * cx - nx * cz, e2z = nx * cy - ny * cx;
    FP f;
    f.ex = e1x * invA2; f.ey = e1y * invA2; f.ez = e1z * invA2;   // e02
    f.hx = e2x * invA2; f.hy = e2y * invA2; f.hz = e2z * invA2;   // e10
    float s1x = e1x * sc, s1y = e1y * sc, s1z = e1z * sc;         // area*e02
    float s2x = e2x * sc, s2y = e2y * sc, s2z = e2z * sc;         // area*e10
    float d1x = D1.x - D0.x, d1y = D1.y - D0.y, d1z = D1.z - D0.z;
    float d2x = D2.x - D0.x, d2y = D2.y - D0.y, d2z = D2.z - D0.z;
    f.w[0] = s1x * d1x + s2x * d2x;
    f.w[1] = s1x * d1y + s2x * d2y;
    f.w[2] = s1x * d1z + s2x * d2z;
    f.w[3] = s1y * d1x + s2y * d2x;
    f.w[4] = s1y * d1y + s2y * d2y;
    f.w[5] = s1y * d1z + s2y * d2z;
    f.w[6] = s1z * d1x + s2z * d2x;
    f.w[7] = s1z * d1y + s2z * d2y;
    f.w[8] = s1z * d1z + s2z * d2z;
    return f;
}

__device__ __forceinline__ FP shfl_up_fp(const FP& f)
{
    FP r;
    r.ex = __shfl_up(f.ex, 1, 64); r.ey = __shfl_up(f.ey, 1, 64);
    r.ez = __shfl_up(f.ez, 1, 64);
    r.hx = __shfl_up(f.hx, 1, 64); r.hy = __shfl_up(f.hy, 1, 64);
    r.hz = __shfl_up(f.hz, 1, 64);
#pragma unroll
    for (int i = 0; i < 9; ++i) r.w[i] = __shfl_up(f.w[i], 1, 64);
    return r;
}

// ROLE: 0 -> i0 (k=-(e02+e10)), 1 -> i1 (k=e02), 2 -> i2 (k=e10)
template <int ROLE>
__device__ __forceinline__ void addc(const FP& f, float acc[6][3])
{
    float K[3];
    if (ROLE == 1)      { K[0] = f.ex; K[1] = f.ey; K[2] = f.ez; }
    else if (ROLE == 2) { K[0] = f.hx; K[1] = f.hy; K[2] = f.hz; }
    else { K[0] = -(f.ex + f.hx); K[1] = -(f.ey + f.hy); K[2] = -(f.ez + f.hz); }
    const int pa[6] = {0, 1, 2, 0, 0, 1};
    const int pb[6] = {0, 1, 2, 1, 2, 2};
#pragma unroll
    for (int p = 0; p < 6; ++p)
#pragma unroll
        for (int cc = 0; cc < 3; ++cc)
            acc[p][cc] += K[pa[p]] * f.w[pb[p] * 3 + cc];
}

// role-i2 contribution from the slim F4 carry
__device__ __forceinline__ void addF4(const FPh& f, float acc[6][3])
{
    const float K[3] = {f.hx, f.hy, f.hz};
    const int pa[6] = {0, 1, 2, 0, 0, 1};
    const int pb[6] = {0, 1, 2, 1, 2, 2};
#pragma unroll
    for (int p = 0; p < 6; ++p)
#pragma unroll
        for (int cc = 0; cc < 3; ++cc)
            acc[p][cc] += K[pa[p]] * f.w[pb[p] * 3 + cc];
}

// role-i1 contribution from slim (K,w) pair (F5)
__device__ __forceinline__ void addKW(const float K[3], const float w[9],
                                      float acc[6][3])
{
    const int pa[6] = {0, 1, 2, 0, 0, 1};
    const int pb[6] = {0, 1, 2, 1, 2, 2};
#pragma unroll
    for (int p = 0; p < 6; ++p)
#pragma unroll
        for (int cc = 0; cc < 3; ++cc)
            acc[p][cc] += K[pa[p]] * w[pb[p] * 3 + cc];
}

__device__ __forceinline__ float sq_acc(const float acc[6][3])
{
    float s1 = 0.0f, s2 = 0.0f;
#pragma unroll
    for (int p = 0; p < 3; ++p)
#pragma unroll
        for (int cc = 0; cc < 3; ++cc) s1 += acc[p][cc] * acc[p][cc];
#pragma unroll
    for (int p = 3; p < 6; ++p)
#pragma unroll
        for (int cc = 0; cc < 3; ++cc) s2 += acc[p][cc] * acc[p][cc];
    return s1 + 2.0f * s2;
}

#define MK 4       // rows marched per thread
#define OUTW 63    // output columns per wave (lane 0 = ghost)
#define BOUT (4 * OUTW)  // 252 output columns per 256-thread block

__global__ __launch_bounds__(256)
void hess_face(const float* __restrict__ vsf, const float* __restrict__ vtf,
               float* __restrict__ partials, int W, int H)
{
    const float3* vs = (const float3*)vsf;
    const float3* vt = (const float3*)vtf;
    const int tid = threadIdx.x, lane = tid & 63, wvid = tid >> 6;
    const int c = blockIdx.x * BOUT + wvid * OUTW + lane - 1;
    const int r0 = blockIdx.y * MK;
    const bool valid = (lane > 0) && (c < W);   // lane>0 => c >= 0
    const bool cp = (c < W - 1), cm = (c > 0);
    const int cL = (c < 0) ? 0 : ((c > W - 1) ? W - 1 : c);
    const int cR = (c + 1 > W - 1) ? W - 1 : ((c + 1 < 0) ? 0 : c + 1);

    // ---- prologue: rows r0-1 (clamped) and r0; build initial F4, F6 ----
    const int otop = (r0 > 0 ? r0 - 1 : 0) * W;
    const int obot = r0 * W;
    float3 V00 = vs[otop + cL];  float3 D00 = d3(vt[otop + cL], V00);
    float3 V10 = vs[obot + cL];  float3 D10 = d3(vt[obot + cL], V10);
    float3 V01 = shfl_dn3(V00),  D01 = shfl_dn3(D00);
    float3 V11 = shfl_dn3(V10),  D11 = shfl_dn3(D10);
    if (lane == 63) {
        float3 v = vs[otop + cR]; V01 = v; D01 = d3(vt[otop + cR], v);
        v = vs[obot + cR];        V11 = v; D11 = d3(vt[obot + cR], v);
    }
    FPh F4;
    {
        FP F1p = mkface(V00, V01, V11, D00, D01, D11);   // f1@(r0-1,c)
        F4.hx = __shfl_up(F1p.hx, 1, 64);
        F4.hy = __shfl_up(F1p.hy, 1, 64);
        F4.hz = __shfl_up(F1p.hz, 1, 64);
#pragma unroll
        for (int i = 0; i < 9; ++i) F4.w[i] = __shfl_up(F1p.w[i], 1, 64);
    }
    FP F6 = mkface(V00, V11, V10, D00, D11, D10);        // f2@(r0-1,c)
    // advance to rows r0, r0+1
    V00 = V10; D00 = D10; V01 = V11; D01 = D11;
    const int o1 = (r0 + 1 < H ? r0 + 1 : H - 1) * W;
    V10 = vs[o1 + cL]; D10 = d3(vt[o1 + cL], V10);
    V11 = shfl_dn3(V10); D11 = shfl_dn3(D10);
    if (lane == 63) {
        float3 v = vs[o1 + cR]; V11 = v; D11 = d3(vt[o1 + cR], v);
    }

    float s = 0.0f;
#pragma unroll
    for (int k = 0; k < MK; ++k) {
        const int r = r0 + k;
        const bool rp = (r < H - 1), rm = (r > 0);   // wave-uniform

        // prefetch row r+2 (own column; lane-63 also right column)
        const int ob = (r + 2 < H ? r + 2 : H - 1) * W;
        float3 P = vs[ob + cL];
        float3 TP = vt[ob + cL];
        float3 PR = P, TPR = TP;
        if (lane == 63) { PR = vs[ob + cR]; TPR = vt[ob + cR]; }

        // build this row's faces (once per face, owner lane) — R9 order
        FP F1 = mkface(V00, V01, V11, D00, D01, D11);  // f1@(r,c)
        FP F2 = mkface(V00, V11, V10, D00, D11, D10);  // f2@(r,c)
        FP F3 = shfl_up_fp(F1);                        // f1@(r,c-1)
        float F5K[3], F5w[9];                          // f2@(r-1,c-1): e+w of F6
        F5K[0] = __shfl_up(F6.ex, 1, 64);
        F5K[1] = __shfl_up(F6.ey, 1, 64);
        F5K[2] = __shfl_up(F6.ez, 1, 64);
#pragma unroll
        for (int i = 0; i < 9; ++i) F5w[i] = __shfl_up(F6.w[i], 1, 64);

        float acc[6][3] = {};
        if (rp && cp) { addc<0>(F1, acc); addc<0>(F2, acc); }
        if (rp && cm) addc<1>(F3, acc);
        if (rm && cm) { addF4(F4, acc); addKW(F5K, F5w, acc); }
        if (rm && cp) addc<2>(F6, acc);
        s += sq_acc(acc);

        // rotate
        V00 = V10; D00 = D10; V01 = V11; D01 = D11;
        V10 = P;   D10 = d3(TP, P);
        V11 = shfl_dn3(V10); D11 = shfl_dn3(D10);
        if (lane == 63) { V11 = PR; D11 = d3(TPR, PR); }
        F4.hx = F3.hx; F4.hy = F3.hy; F4.hz = F3.hz;
#pragma unroll
        for (int i = 0; i < 9; ++i) F4.w[i] = F3.w[i];
        F6 = F2;
    }

    if (!valid) s = 0.0f;   // overwrite: kills ghost/out-of-range NaN

    // ---- block reduce + plain partial store ----
#pragma unroll
    for (int o = 32; o > 0; o >>= 1) s += __shfl_down(s, o, 64);
    __shared__ float sm[4];
    if (lane == 0) sm[wvid] = s;
    __syncthreads();
    if (tid == 0)
        partials[blockIdx.y * gridDim.x + blockIdx.x] = sm[0] + sm[1] + sm[2] + sm[3];
}

// ------------- fallback: 1-D per-vertex gather (any grid dims) -------------

__global__ void hess_gather(const float* __restrict__ vsf, const float* __restrict__ vtf,
                            float* __restrict__ partials, int W, int H)
{
    const float3* vs = (const float3*)vsf;
    const float3* vt = (const float3*)vtf;
    int v = blockIdx.x * blockDim.x + threadIdx.x;
    int n = W * H;
    float s = 0.0f;
    if (v < n) {
        int r = v / W;
        int c = v - r * W;
        bool rp = (r < H - 1), rm = (r >= 1), cp = (c < W - 1), cm = (c >= 1);
        int i01 = cp ? v + 1 : v;
        int i11 = (rp && cp) ? v + W + 1 : v;
        int i10 = rp ? v + W : v;
        int im  = cm ? v - 1 : v;
        int idd = (rm && cm) ? v - W - 1 : v;
        int iu  = rm ? v - W : v;
        float3 P00 = vs[v],   D00 = d3(vt[v], P00);
        float3 P01 = vs[i01], D01 = d3(vt[i01], P01);
        float3 P11 = vs[i11], D11 = d3(vt[i11], P11);
        float3 P10 = vs[i10], D10 = d3(vt[i10], P10);
        float3 Pm  = vs[im],  Dm  = d3(vt[im], Pm);
        float3 Pdd = vs[idd], Ddd = d3(vt[idd], Pdd);
        float3 Pu  = vs[iu],  Du  = d3(vt[iu], Pu);
        float acc[6][3] = {};
        if (rp && cp) {
            addc<0>(mkface(P00, P01, P11, D00, D01, D11), acc);
            addc<0>(mkface(P00, P11, P10, D00, D11, D10), acc);
        }
        if (rp && cm)
            addc<1>(mkface(Pm, P00, P10, Dm, D00, D10), acc);
        if (rm && cm) {
            addc<2>(mkface(Pdd, Pu, P00, Ddd, Du, D00), acc);
            addc<1>(mkface(Pdd, P00, Pm, Ddd, D00, Dm), acc);
        }
        if (rm && cp)
            addc<2>(mkface(Pu, P01, P00, Du, D01, D00), acc);
        s = sq_acc(acc);
    }
#pragma unroll
    for (int o = 32; o > 0; o >>= 1) s += __shfl_down(s, o, 64);
    __shared__ float sm[4];
    int lane = threadIdx.x & 63, wid = threadIdx.x >> 6;
    if (lane == 0) sm[wid] = s;
    __syncthreads();
    if (threadIdx.x == 0)
        partials[blockIdx.x] = sm[0] + sm[1] + sm[2] + sm[3];
}

__global__ void finalize_sum(const float* __restrict__ partials, int nparts,
                             float* __restrict__ out, int n)
{
    float s = 0.0f;
    for (int i = threadIdx.x; i < nparts; i += 256) s += partials[i];
#pragma unroll
    for (int o = 32; o > 0; o >>= 1) s += __shfl_down(s, o, 64);
    __shared__ float sm[4];
    int lane = threadIdx.x & 63, wid = threadIdx.x >> 6;
    if (lane == 0) sm[wid] = s;
    __syncthreads();
    if (threadIdx.x == 0)
        out[0] = (sm[0] + sm[1] + sm[2] + sm[3]) / (3.0f * (float)n);
}

// ---------------------------------------------------------------------------

extern "C" void kernel_launch(void* const* d_in, const int* in_sizes, int n_in,
                              void* d_out, int out_size, void* d_ws, size_t ws_size,
                              hipStream_t stream)
{
    const float* vs = (const float*)d_in[0];
    const float* vt = (const float*)d_in[1];
    int n = in_sizes[0] / 3;
    int F = in_sizes[2] / 3;

    int W = (int)(sqrt((double)n) + 0.5);
    int H = (W > 0) ? n / W : 0;
    bool grid_ok = (W > 1) && ((long long)W * H == n) &&
                   (2LL * (W - 1) * (H - 1) == F);

    float* partials = (float*)d_ws;

    if (grid_ok && (H % MK == 0)) {
        dim3 block(256, 1, 1);
        dim3 grid((W + BOUT - 1) / BOUT, H / MK, 1);
        int nparts = grid.x * grid.y;
        hess_face<<<grid, block, 0, stream>>>(vs, vt, partials, W, H);
        finalize_sum<<<1, 256, 0, stream>>>(partials, nparts, (float*)d_out, n);
    } else {
        int threads = 256;
        int blocks = (n + threads - 1) / threads;
        hess_gather<<<blocks, threads, 0, stream>>>(vs, vt, partials, W, H);
        finalize_sum<<<1, 256, 0, stream>>>(partials, blocks, (float*)d_out, n);
    }
}